// Round 5
// baseline (6601.404 us; speedup 1.0000x reference)
//
#include <hip/hip_runtime.h>
#include <math.h>

#define N_RES 2048
#define N_IN  128
#define T_SEQ 2048
#define NB    128      // blocks in recurrence kernel
#define ROWS  16       // rows per block (4 waves x 4 rows)
#define SENT  0x7F7F7F7Fu   // sentinel (3.39e38); bit30 set. |x|<=0.0222 -> bit30 clear

// ---------------- Kernel 1: U = input @ W_in^T  -> d_out (row t = U[t]) ----
__global__ __launch_bounds__(256) void u_gemm(
    const float* __restrict__ in, const float* __restrict__ win,
    float* __restrict__ out)
{
  __shared__ float As[64][65];
  __shared__ float Bs[64][65];
  const int tid = threadIdx.x;
  const int t0 = blockIdx.y * 64;
  const int n0 = blockIdx.x * 64;
  const int tx = tid & 15, ty = tid >> 4;

  float acc[4][4];
  #pragma unroll
  for (int r = 0; r < 4; ++r)
    #pragma unroll
    for (int c = 0; c < 4; ++c) acc[r][c] = 0.f;

  for (int k0 = 0; k0 < N_IN; k0 += 64) {
    __syncthreads();
    #pragma unroll
    for (int i = 0; i < 4; ++i) {
      int idx = tid + i * 256;
      int row = idx >> 4;
      int k4  = (idx & 15) << 2;
      float4 a = *(const float4*)(in  + (size_t)(t0 + row) * N_IN + k0 + k4);
      As[row][k4+0] = a.x; As[row][k4+1] = a.y; As[row][k4+2] = a.z; As[row][k4+3] = a.w;
      float4 b = *(const float4*)(win + (size_t)(n0 + row) * N_IN + k0 + k4);
      Bs[row][k4+0] = b.x; Bs[row][k4+1] = b.y; Bs[row][k4+2] = b.z; Bs[row][k4+3] = b.w;
    }
    __syncthreads();
    for (int k = 0; k < 64; ++k) {
      float a[4], b[4];
      #pragma unroll
      for (int r = 0; r < 4; ++r) a[r] = As[ty*4+r][k];
      #pragma unroll
      for (int c = 0; c < 4; ++c) b[c] = Bs[tx*4+c][k];
      #pragma unroll
      for (int r = 0; r < 4; ++r)
        #pragma unroll
        for (int c = 0; c < 4; ++c) acc[r][c] += a[r] * b[c];
    }
  }
  #pragma unroll
  for (int r = 0; r < 4; ++r) {
    float4 v = make_float4(acc[r][0], acc[r][1], acc[r][2], acc[r][3]);
    *(float4*)(out + (size_t)(t0 + ty*4 + r) * N_RES + n0 + tx*4) = v;
  }
}

// ---------------- Kernel 2: recurrence, wave-autonomous --------------------
// 128 blocks x 256 threads = 512 waves. Wave (b,w) owns 4 complete rows
// [b*16+4w, b*16+4w+4): lane holds 32 interleaved columns (col = lane+64j)
// of W for each row -> full row sums finish in-wave (7 shuffles). No LDS,
// no __syncthreads in the step loop; waves self-time off data arrival
// (x history in ws, sentinel-initialized, agent-scope stores/loads).
__global__ __launch_bounds__(256, 1) void esn_recur_wave(
    const float* __restrict__ wres, float* out, unsigned int* xbuf)
{
  const int tid = threadIdx.x;
  const int lane = tid & 63;
  const int wave = tid >> 6;
  const int row0 = blockIdx.x * ROWS + wave * 4;
  const float inv = 0.022097086912079608f;   // 1/sqrt(2048)
  // after fold, lane L holds the complete sum of row0 + myR, myR = 2*(L&1)+((L>>1)&1)
  const int myR = 2 * (lane & 1) + ((lane >> 1) & 1);

  // W: w[r][j] = W[row0+r][lane + 64*j]; fully coalesced loads.
  float w[4][32];
  #pragma unroll
  for (int r = 0; r < 4; ++r) {
    const float* p = wres + (size_t)(row0 + r) * N_RES + lane;
    #pragma unroll
    for (int j = 0; j < 32; ++j) w[r][j] = p[j * 64];
  }

  // t = 0: lanes 0..3 produce rows row0+myR
  if (lane < 4) {
    float x0 = erff(out[row0 + myR]) * inv;
    out[row0 + myR] = x0;
    __hip_atomic_store(xbuf + row0 + myR, __float_as_uint(x0),
                       __ATOMIC_RELAXED, __HIP_MEMORY_SCOPE_AGENT);
  }

  for (int t = 1; t < T_SEQ; ++t) {
    // own U[t] slot (4 distinct addresses, one inst) — hides under the poll
    float u = out[(size_t)t * N_RES + row0 + myR];

    // poll own 32 x words of row t-1 until no sentinel (bit30 test)
    const unsigned int* xr = xbuf + (size_t)(t - 1) * N_RES + lane;
    unsigned int xb[32];
    unsigned int orv;
    do {
      #pragma unroll
      for (int j = 0; j < 32; ++j)
        xb[j] = __hip_atomic_load(xr + j * 64, __ATOMIC_RELAXED,
                                  __HIP_MEMORY_SCOPE_AGENT);
      orv = 0;
      #pragma unroll
      for (int j = 0; j < 32; ++j) orv |= xb[j];
    } while (orv & 0x40000000u);

    // 4 full-row partial sums (128 FMA/lane)
    float v[4];
    #pragma unroll
    for (int r = 0; r < 4; ++r) {
      float s = 0.f;
      #pragma unroll
      for (int j = 0; j < 32; ++j) s += w[r][j] * __uint_as_float(xb[j]);
      v[r] = s;
    }

    // fold 4 -> 1 (3 shuffles), then butterfly over xor {4,8,16,32}
    #pragma unroll
    for (int r = 0; r < 2; ++r) {
      float send = (lane & 1) ? v[r] : v[r + 2];
      float recv = __shfl_xor(send, 1, 64);
      v[r] = ((lane & 1) ? v[r + 2] : v[r]) + recv;
    }
    {
      float send = (lane & 2) ? v[0] : v[1];
      float recv = __shfl_xor(send, 2, 64);
      v[0] = ((lane & 2) ? v[1] : v[0]) + recv;
    }
    v[0] += __shfl_xor(v[0], 4, 64);
    v[0] += __shfl_xor(v[0], 8, 64);
    v[0] += __shfl_xor(v[0], 16, 64);
    v[0] += __shfl_xor(v[0], 32, 64);

    float xt = erff(u + v[0]) * inv;     // all lanes compute (no divergence)
    if (lane < 4) {
      out[(size_t)t * N_RES + row0 + myR] = xt;                        // plain
      __hip_atomic_store(xbuf + (size_t)t * N_RES + row0 + myR,
                         __float_as_uint(xt),
                         __ATOMIC_RELAXED, __HIP_MEMORY_SCOPE_AGENT);  // signal
    }
  }
}

// ---------------- fallback (R2 flag barrier) if ws < 16 MiB ----------------
#define FSTR 4
__global__ __launch_bounds__(256, 1) void esn_recur_flags(
    const float* __restrict__ wres, float* out, int* ws)
{
  const int b = blockIdx.x;
  const int tid = threadIdx.x;
  const int lane = tid & 63;
  const int wave = tid >> 6;
  const int row0 = b * ROWS;
  const float inv = 0.022097086912079608f;

  float w[ROWS][8];
  #pragma unroll
  for (int r = 0; r < ROWS; ++r) {
    const float* p = wres + (size_t)(row0 + r) * N_RES + tid;
    #pragma unroll
    for (int j = 0; j < 8; ++j) w[r][j] = p[j * 256];
  }

  __shared__ float red[ROWS][4];
  int* flags = ws;

  if (tid < ROWS) {
    float u = out[row0 + tid];
    __hip_atomic_store(out + row0 + tid, erff(u) * inv,
                       __ATOMIC_RELAXED, __HIP_MEMORY_SCOPE_AGENT);
  }
  if (wave == 0) {
    asm volatile("s_waitcnt vmcnt(0)" ::: "memory");
    if (lane == 0)
      __hip_atomic_store(flags + b * FSTR, 1, __ATOMIC_RELAXED, __HIP_MEMORY_SCOPE_AGENT);
  }

  for (int t = 1; t < T_SEQ; ++t) {
    if (wave == 0) {
      const int* f0 = flags + lane * FSTR;
      const int* f1 = flags + (lane + 64) * FSTR;
      bool ok;
      do {
        int a = __hip_atomic_load(f0, __ATOMIC_RELAXED, __HIP_MEMORY_SCOPE_AGENT);
        int c = __hip_atomic_load(f1, __ATOMIC_RELAXED, __HIP_MEMORY_SCOPE_AGENT);
        ok = (a >= t) && (c >= t);
      } while (!__all(ok));
    }
    __syncthreads();

    float u = 0.f;
    if (tid < ROWS) u = out[(size_t)t * N_RES + row0 + tid];

    const float* xrow = out + (size_t)(t - 1) * N_RES + tid;
    float x[8];
    #pragma unroll
    for (int j = 0; j < 8; ++j)
      x[j] = __hip_atomic_load(xrow + j * 256, __ATOMIC_RELAXED, __HIP_MEMORY_SCOPE_AGENT);

    float acc[ROWS];
    #pragma unroll
    for (int r = 0; r < ROWS; ++r) {
      acc[r] = w[r][0]*x[0] + w[r][1]*x[1] + w[r][2]*x[2] + w[r][3]*x[3]
             + w[r][4]*x[4] + w[r][5]*x[5] + w[r][6]*x[6] + w[r][7]*x[7];
    }
    #pragma unroll
    for (int m = 1; m < 64; m <<= 1) {
      #pragma unroll
      for (int r = 0; r < ROWS; ++r)
        acc[r] += __shfl_xor(acc[r], m, 64);
    }
    if (lane == 0) {
      #pragma unroll
      for (int r = 0; r < ROWS; ++r) red[r][wave] = acc[r];
    }
    __syncthreads();
    if (tid < ROWS) {
      float s = red[tid][0] + red[tid][1] + red[tid][2] + red[tid][3];
      __hip_atomic_store(out + (size_t)t * N_RES + row0 + tid, erff(u + s) * inv,
                         __ATOMIC_RELAXED, __HIP_MEMORY_SCOPE_AGENT);
    }
    if (wave == 0) {
      asm volatile("s_waitcnt vmcnt(0)" ::: "memory");
      if (lane == 0)
        __hip_atomic_store(flags + b * FSTR, t + 1,
                           __ATOMIC_RELAXED, __HIP_MEMORY_SCOPE_AGENT);
    }
  }
}

extern "C" void kernel_launch(void* const* d_in, const int* in_sizes, int n_in,
                              void* d_out, int out_size, void* d_ws, size_t ws_size,
                              hipStream_t stream)
{
  const float* input = (const float*)d_in[0];
  const float* w_in  = (const float*)d_in[1];
  const float* w_res = (const float*)d_in[2];
  float* out = (float*)d_out;

  const size_t xbytes = (size_t)T_SEQ * N_RES * sizeof(float);  // 16 MiB

  dim3 g1(N_RES / 64, T_SEQ / 64), b1(256);
  hipLaunchKernelGGL(u_gemm, g1, b1, 0, stream, input, w_in, out);

  if (ws_size >= xbytes) {
    unsigned int* xbuf = (unsigned int*)d_ws;
    hipMemsetAsync(d_ws, 0x7F, xbytes, stream);   // sentinel-fill x history
    void* args[] = { (void*)&w_res, (void*)&out, (void*)&xbuf };
    hipLaunchCooperativeKernel((void*)esn_recur_wave, dim3(NB), dim3(256),
                               args, 0, stream);
  } else {
    int* ws = (int*)d_ws;
    size_t clr = ws_size < 4096 ? ws_size : 4096;
    hipMemsetAsync(d_ws, 0, clr, stream);
    void* args[] = { (void*)&w_res, (void*)&out, (void*)&ws };
    hipLaunchCooperativeKernel((void*)esn_recur_flags, dim3(NB), dim3(256),
                               args, 0, stream);
  }
}

// Round 6
// 4210.938 us; speedup vs baseline: 1.5677x; 1.5677x over previous
//
#include <hip/hip_runtime.h>
#include <math.h>

#define N_RES 2048
#define N_IN  128
#define T_SEQ 2048
#define NB    128      // blocks in recurrence kernel
#define ROWS  16       // rows per block
#define SENT  0x7F7F7F7Fu   // sentinel (3.39e38); bit30 set. |x|<=0.0222 -> bit30 clear

// ---------------- Kernel 1: U = input @ W_in^T  -> d_out (row t = U[t]) ----
__global__ __launch_bounds__(256) void u_gemm(
    const float* __restrict__ in, const float* __restrict__ win,
    float* __restrict__ out)
{
  __shared__ float As[64][65];
  __shared__ float Bs[64][65];
  const int tid = threadIdx.x;
  const int t0 = blockIdx.y * 64;
  const int n0 = blockIdx.x * 64;
  const int tx = tid & 15, ty = tid >> 4;

  float acc[4][4];
  #pragma unroll
  for (int r = 0; r < 4; ++r)
    #pragma unroll
    for (int c = 0; c < 4; ++c) acc[r][c] = 0.f;

  for (int k0 = 0; k0 < N_IN; k0 += 64) {
    __syncthreads();
    #pragma unroll
    for (int i = 0; i < 4; ++i) {
      int idx = tid + i * 256;
      int row = idx >> 4;
      int k4  = (idx & 15) << 2;
      float4 a = *(const float4*)(in  + (size_t)(t0 + row) * N_IN + k0 + k4);
      As[row][k4+0] = a.x; As[row][k4+1] = a.y; As[row][k4+2] = a.z; As[row][k4+3] = a.w;
      float4 b = *(const float4*)(win + (size_t)(n0 + row) * N_IN + k0 + k4);
      Bs[row][k4+0] = b.x; Bs[row][k4+1] = b.y; Bs[row][k4+2] = b.z; Bs[row][k4+3] = b.w;
    }
    __syncthreads();
    for (int k = 0; k < 64; ++k) {
      float a[4], b[4];
      #pragma unroll
      for (int r = 0; r < 4; ++r) a[r] = As[ty*4+r][k];
      #pragma unroll
      for (int c = 0; c < 4; ++c) b[c] = Bs[tx*4+c][k];
      #pragma unroll
      for (int r = 0; r < 4; ++r)
        #pragma unroll
        for (int c = 0; c < 4; ++c) acc[r][c] += a[r] * b[c];
    }
  }
  #pragma unroll
  for (int r = 0; r < 4; ++r) {
    float4 v = make_float4(acc[r][0], acc[r][1], acc[r][2], acc[r][3]);
    *(float4*)(out + (size_t)(t0 + ty*4 + r) * N_RES + n0 + tx*4) = v;
  }
}

// ---- fold-and-keep wave reduction: 16 partials -> 1 full row sum per lane.
// After all levels, lane L holds the complete sum (over all 64 lanes) of row
// rml(L) = (L&1)*8 + ((L>>1)&1)*4 + ((L>>2)&1)*2 + ((L>>3)&1), dup x4.
__device__ __forceinline__ float fold_reduce16(float v[16], int lane)
{
  #pragma unroll
  for (int r = 0; r < 8; ++r) {
    float send = (lane & 1) ? v[r] : v[r + 8];
    float recv = __shfl_xor(send, 1, 64);
    v[r] = ((lane & 1) ? v[r + 8] : v[r]) + recv;
  }
  #pragma unroll
  for (int r = 0; r < 4; ++r) {
    float send = (lane & 2) ? v[r] : v[r + 4];
    float recv = __shfl_xor(send, 2, 64);
    v[r] = ((lane & 2) ? v[r + 4] : v[r]) + recv;
  }
  #pragma unroll
  for (int r = 0; r < 2; ++r) {
    float send = (lane & 4) ? v[r] : v[r + 2];
    float recv = __shfl_xor(send, 4, 64);
    v[r] = ((lane & 4) ? v[r + 2] : v[r]) + recv;
  }
  {
    float send = (lane & 8) ? v[0] : v[1];
    float recv = __shfl_xor(send, 8, 64);
    v[0] = ((lane & 8) ? v[1] : v[0]) + recv;
  }
  v[0] += __shfl_xor(v[0], 16, 64);
  v[0] += __shfl_xor(v[0], 32, 64);
  return v[0];
}

// ---------------- Kernel 2: recurrence, data-as-flag, barrier-free combine -
// 128 blocks x 256 threads. Block b owns rows [16b,16b+16); thread t owns
// cols {t+256j}. Thread gates only on its OWN 8 x words (distributed gating).
// Cross-wave combine: waves 1-3 write partials to parity-buffered LDS, raise
// monotonic LDS flags, move on; wave 0 spins on flags (already set by the
// time it arrives), combines in-register, erf, stores. No __syncthreads and
// no LDS bank conflicts in the 2047-step loop.
__global__ __launch_bounds__(256, 1) void esn_recur_v5(
    const float* __restrict__ wres, float* __restrict__ out,
    unsigned int* __restrict__ xbuf)
{
  const int tid = threadIdx.x;
  const int lane = tid & 63;
  const int wave = tid >> 6;
  const int row0 = blockIdx.x * ROWS;
  const float inv = 0.022097086912079608f;   // 1/sqrt(2048)
  const int rml = (lane & 1) * 8 + ((lane >> 1) & 1) * 4
                + ((lane >> 2) & 1) * 2 + ((lane >> 3) & 1);

  // W: w[r][j] = W[row0+r][tid + 256*j]; coalesced loads, lives in VGPR/AGPR.
  float w[ROWS][8];
  #pragma unroll
  for (int r = 0; r < ROWS; ++r) {
    const float* p = wres + (size_t)(row0 + r) * N_RES + tid;
    #pragma unroll
    for (int j = 0; j < 8; ++j) w[r][j] = p[j * 256];
  }

  __shared__ float red[2][4][ROWS];    // [t&1][wave][row] — conflict-free
  __shared__ int wflags[4];            // monotonic per-wave arrival flags
  if (tid < 4) wflags[tid] = 0;

  // t = 0
  if (tid < ROWS) {
    float x0 = erff(out[row0 + tid]) * inv;
    __hip_atomic_store(xbuf + row0 + tid, __float_as_uint(x0),
                       __ATOMIC_RELAXED, __HIP_MEMORY_SCOPE_AGENT);
    out[row0 + tid] = x0;
  }
  __syncthreads();

  for (int t = 1; t < T_SEQ; ++t) {
    const int p = t & 1;
    // own U[t] slot for row rml (one inst; latency hides under the poll)
    float u = out[(size_t)t * N_RES + row0 + rml];

    // poll own 8 x words of row t-1 (bit-30 sentinel test)
    const unsigned int* xr = xbuf + (size_t)(t - 1) * N_RES + tid;
    unsigned int xb[8];
    unsigned int orv;
    do {
      #pragma unroll
      for (int j = 0; j < 8; ++j)
        xb[j] = __hip_atomic_load(xr + j * 256, __ATOMIC_RELAXED,
                                  __HIP_MEMORY_SCOPE_AGENT);
      orv  = (xb[0] | xb[1]) | (xb[2] | xb[3]);
      orv |= (xb[4] | xb[5]) | (xb[6] | xb[7]);
    } while (orv & 0x40000000u);

    // partial matvec: 16 rows x 8 cols, then in-wave full row sums
    float acc[ROWS];
    #pragma unroll
    for (int r = 0; r < ROWS; ++r) {
      acc[r] = w[r][0]*__uint_as_float(xb[0]) + w[r][1]*__uint_as_float(xb[1])
             + w[r][2]*__uint_as_float(xb[2]) + w[r][3]*__uint_as_float(xb[3])
             + w[r][4]*__uint_as_float(xb[4]) + w[r][5]*__uint_as_float(xb[5])
             + w[r][6]*__uint_as_float(xb[6]) + w[r][7]*__uint_as_float(xb[7]);
    }
    float s = fold_reduce16(acc, lane);   // lane holds full sum of row rml

    if (wave != 0) {
      if (lane < ROWS) red[p][wave][rml] = s;
      asm volatile("s_waitcnt lgkmcnt(0)" ::: "memory");  // red visible first
      if (lane == 0) ((volatile int*)wflags)[wave] = t;
      // free to run ahead to step t+1 (data dependency gates it anyway)
    } else {
      // wave 0: wait for sibling partials (flags normally already set)
      volatile int* vf = wflags;
      bool ok;
      do {
        int fv = (lane < 3) ? vf[lane + 1] : 0x7FFFFFFF;
        ok = (fv >= t);
      } while (!__all(ok));
      asm volatile("" ::: "memory");
      if (lane < ROWS) {
        float tot = s + red[p][1][rml] + red[p][2][rml] + red[p][3][rml];
        float xt = erff(u + tot) * inv;
        __hip_atomic_store(xbuf + (size_t)t * N_RES + row0 + rml,
                           __float_as_uint(xt),
                           __ATOMIC_RELAXED, __HIP_MEMORY_SCOPE_AGENT); // signal
        out[(size_t)t * N_RES + row0 + rml] = xt;                       // plain
      }
    }
  }
}

// ---------------- fallback (R2 flag barrier) if ws < 16 MiB ----------------
#define FSTR 4
__global__ __launch_bounds__(256, 1) void esn_recur_flags(
    const float* __restrict__ wres, float* out, int* ws)
{
  const int b = blockIdx.x;
  const int tid = threadIdx.x;
  const int lane = tid & 63;
  const int wave = tid >> 6;
  const int row0 = b * ROWS;
  const float inv = 0.022097086912079608f;

  float w[ROWS][8];
  #pragma unroll
  for (int r = 0; r < ROWS; ++r) {
    const float* p = wres + (size_t)(row0 + r) * N_RES + tid;
    #pragma unroll
    for (int j = 0; j < 8; ++j) w[r][j] = p[j * 256];
  }

  __shared__ float red[ROWS][4];
  int* flags = ws;

  if (tid < ROWS) {
    float u = out[row0 + tid];
    __hip_atomic_store(out + row0 + tid, erff(u) * inv,
                       __ATOMIC_RELAXED, __HIP_MEMORY_SCOPE_AGENT);
  }
  if (wave == 0) {
    asm volatile("s_waitcnt vmcnt(0)" ::: "memory");
    if (lane == 0)
      __hip_atomic_store(flags + b * FSTR, 1, __ATOMIC_RELAXED, __HIP_MEMORY_SCOPE_AGENT);
  }

  for (int t = 1; t < T_SEQ; ++t) {
    if (wave == 0) {
      const int* f0 = flags + lane * FSTR;
      const int* f1 = flags + (lane + 64) * FSTR;
      bool ok;
      do {
        int a = __hip_atomic_load(f0, __ATOMIC_RELAXED, __HIP_MEMORY_SCOPE_AGENT);
        int c = __hip_atomic_load(f1, __ATOMIC_RELAXED, __HIP_MEMORY_SCOPE_AGENT);
        ok = (a >= t) && (c >= t);
      } while (!__all(ok));
    }
    __syncthreads();

    float u = 0.f;
    if (tid < ROWS) u = out[(size_t)t * N_RES + row0 + tid];

    const float* xrow = out + (size_t)(t - 1) * N_RES + tid;
    float x[8];
    #pragma unroll
    for (int j = 0; j < 8; ++j)
      x[j] = __hip_atomic_load(xrow + j * 256, __ATOMIC_RELAXED, __HIP_MEMORY_SCOPE_AGENT);

    float acc[ROWS];
    #pragma unroll
    for (int r = 0; r < ROWS; ++r) {
      acc[r] = w[r][0]*x[0] + w[r][1]*x[1] + w[r][2]*x[2] + w[r][3]*x[3]
             + w[r][4]*x[4] + w[r][5]*x[5] + w[r][6]*x[6] + w[r][7]*x[7];
    }
    #pragma unroll
    for (int m = 1; m < 64; m <<= 1) {
      #pragma unroll
      for (int r = 0; r < ROWS; ++r)
        acc[r] += __shfl_xor(acc[r], m, 64);
    }
    if (lane == 0) {
      #pragma unroll
      for (int r = 0; r < ROWS; ++r) red[r][wave] = acc[r];
    }
    __syncthreads();
    if (tid < ROWS) {
      float s = red[tid][0] + red[tid][1] + red[tid][2] + red[tid][3];
      __hip_atomic_store(out + (size_t)t * N_RES + row0 + tid, erff(u + s) * inv,
                         __ATOMIC_RELAXED, __HIP_MEMORY_SCOPE_AGENT);
    }
    if (wave == 0) {
      asm volatile("s_waitcnt vmcnt(0)" ::: "memory");
      if (lane == 0)
        __hip_atomic_store(flags + b * FSTR, t + 1,
                           __ATOMIC_RELAXED, __HIP_MEMORY_SCOPE_AGENT);
    }
  }
}

extern "C" void kernel_launch(void* const* d_in, const int* in_sizes, int n_in,
                              void* d_out, int out_size, void* d_ws, size_t ws_size,
                              hipStream_t stream)
{
  const float* input = (const float*)d_in[0];
  const float* w_in  = (const float*)d_in[1];
  const float* w_res = (const float*)d_in[2];
  float* out = (float*)d_out;

  const size_t xbytes = (size_t)T_SEQ * N_RES * sizeof(float);  // 16 MiB

  dim3 g1(N_RES / 64, T_SEQ / 64), b1(256);
  hipLaunchKernelGGL(u_gemm, g1, b1, 0, stream, input, w_in, out);

  if (ws_size >= xbytes) {
    unsigned int* xbuf = (unsigned int*)d_ws;
    hipMemsetAsync(d_ws, 0x7F, xbytes, stream);   // sentinel-fill x history
    void* args[] = { (void*)&w_res, (void*)&out, (void*)&xbuf };
    hipLaunchCooperativeKernel((void*)esn_recur_v5, dim3(NB), dim3(256),
                               args, 0, stream);
  } else {
    int* ws = (int*)d_ws;
    size_t clr = ws_size < 4096 ? ws_size : 4096;
    hipMemsetAsync(d_ws, 0, clr, stream);
    void* args[] = { (void*)&w_res, (void*)&out, (void*)&ws };
    hipLaunchCooperativeKernel((void*)esn_recur_flags, dim3(NB), dim3(256),
                               args, 0, stream);
  }
}

// Round 8
// 3201.168 us; speedup vs baseline: 2.0622x; 1.3154x over previous
//
#include <hip/hip_runtime.h>
#include <math.h>

#define N_RES 2048
#define N_IN  128
#define T_SEQ 2048
#define NB    128      // blocks in recurrence kernel
#define ROWS  16       // rows per block
#define SENT  0x7F7F7F7Fu   // sentinel (3.39e38); bit30 set. |x|<=0.0222 -> bit30 clear

// ---------------- Kernel 1: U = input @ W_in^T  -> d_out (row t = U[t]) ----
__global__ __launch_bounds__(256) void u_gemm(
    const float* __restrict__ in, const float* __restrict__ win,
    float* __restrict__ out)
{
  __shared__ float As[64][65];
  __shared__ float Bs[64][65];
  const int tid = threadIdx.x;
  const int t0 = blockIdx.y * 64;
  const int n0 = blockIdx.x * 64;
  const int tx = tid & 15, ty = tid >> 4;

  float acc[4][4];
  #pragma unroll
  for (int r = 0; r < 4; ++r)
    #pragma unroll
    for (int c = 0; c < 4; ++c) acc[r][c] = 0.f;

  for (int k0 = 0; k0 < N_IN; k0 += 64) {
    __syncthreads();
    #pragma unroll
    for (int i = 0; i < 4; ++i) {
      int idx = tid + i * 256;
      int row = idx >> 4;
      int k4  = (idx & 15) << 2;
      float4 a = *(const float4*)(in  + (size_t)(t0 + row) * N_IN + k0 + k4);
      As[row][k4+0] = a.x; As[row][k4+1] = a.y; As[row][k4+2] = a.z; As[row][k4+3] = a.w;
      float4 b = *(const float4*)(win + (size_t)(n0 + row) * N_IN + k0 + k4);
      Bs[row][k4+0] = b.x; Bs[row][k4+1] = b.y; Bs[row][k4+2] = b.z; Bs[row][k4+3] = b.w;
    }
    __syncthreads();
    for (int k = 0; k < 64; ++k) {
      float a[4], b[4];
      #pragma unroll
      for (int r = 0; r < 4; ++r) a[r] = As[ty*4+r][k];
      #pragma unroll
      for (int c = 0; c < 4; ++c) b[c] = Bs[tx*4+c][k];
      #pragma unroll
      for (int r = 0; r < 4; ++r)
        #pragma unroll
        for (int c = 0; c < 4; ++c) acc[r][c] += a[r] * b[c];
    }
  }
  #pragma unroll
  for (int r = 0; r < 4; ++r) {
    float4 v = make_float4(acc[r][0], acc[r][1], acc[r][2], acc[r][3]);
    *(float4*)(out + (size_t)(t0 + ty*4 + r) * N_RES + n0 + tx*4) = v;
  }
}

// ---- DPP helpers: quad_perm exchanges at VALU speed -----------------------
template<int CTRL>
__device__ __forceinline__ float xdpp(float v)
{
  return __uint_as_float(__builtin_amdgcn_update_dpp(
      0, (int)__float_as_uint(v), CTRL, 0xF, 0xF, true));
}
// quad_perm[1,0,3,2] (xor1) = 0xB1 ; quad_perm[2,3,0,1] (xor2) = 0x4E

// ---- fold-and-keep wave reduction: 16 partials -> 1 full row sum per lane.
// Lane L ends with the complete sum of row rml(L) =
// (L&1)*8 + ((L>>1)&1)*4 + ((L>>2)&1)*2 + ((L>>3)&1)  (4-bit bit-reverse;
// bijection on 0..15 for lanes 0..15, duplicated x4 across the wave).
__device__ __forceinline__ float fold_reduce16(float v[16], int lane)
{
  #pragma unroll
  for (int r = 0; r < 8; ++r) {
    float send = (lane & 1) ? v[r] : v[r + 8];
    float recv = xdpp<0xB1>(send);
    v[r] = ((lane & 1) ? v[r + 8] : v[r]) + recv;
  }
  #pragma unroll
  for (int r = 0; r < 4; ++r) {
    float send = (lane & 2) ? v[r] : v[r + 4];
    float recv = xdpp<0x4E>(send);
    v[r] = ((lane & 2) ? v[r + 4] : v[r]) + recv;
  }
  #pragma unroll
  for (int r = 0; r < 2; ++r) {
    float send = (lane & 4) ? v[r] : v[r + 2];
    float recv = __shfl_xor(send, 4, 64);
    v[r] = ((lane & 4) ? v[r + 2] : v[r]) + recv;
  }
  {
    float send = (lane & 8) ? v[0] : v[1];
    float recv = __shfl_xor(send, 8, 64);
    v[0] = ((lane & 8) ? v[1] : v[0]) + recv;
  }
  v[0] += __shfl_xor(v[0], 16, 64);
  v[0] += __shfl_xor(v[0], 32, 64);
  return v[0];
}

// ---------------- Kernel 2: recurrence, data-as-flag + replicas ------------
// 128 blocks x 256 threads. Block b owns rows [16b,16b+16); thread t owns
// cols {t+256j}. Thread gates on its OWN 8 x words. x history replicated R
// times (layout [t][rep][n]); consumer block reads replica (b & (R-1)) ->
// same-line LLC reader fan-in drops 128 -> 128/R. Producers store R copies
// (issue-parallel). One __syncthreads per step; parity-buffered conflict-free
// LDS combine. ALL row indexing in the combine/store path uses rml (matches
// the early-issued u load) — R6's tid/rml mix was the correctness bug.
__global__ __launch_bounds__(256, 1) void esn_recur_v7(
    const float* __restrict__ wres, float* __restrict__ out,
    unsigned int* __restrict__ xbuf, int R)
{
  const int tid = threadIdx.x;
  const int lane = tid & 63;
  const int row0 = blockIdx.x * ROWS;
  const int wave = tid >> 6;
  const float inv = 0.022097086912079608f;   // 1/sqrt(2048)
  const int rml = (lane & 1) * 8 + ((lane >> 1) & 1) * 4
                + ((lane >> 2) & 1) * 2 + ((lane >> 3) & 1);
  const int rb = blockIdx.x & (R - 1);       // my replica

  // W: w[r][j] = W[row0+r][tid + 256*j]; coalesced, register-resident.
  float w[ROWS][8];
  #pragma unroll
  for (int r = 0; r < ROWS; ++r) {
    const float* p = wres + (size_t)(row0 + r) * N_RES + tid;
    #pragma unroll
    for (int j = 0; j < 8; ++j) w[r][j] = p[j * 256];
  }

  __shared__ float red[2][4][ROWS];   // [t&1][wave][row] — conflict-free

  // t = 0: x0 = erf(U[0]) * inv; store to all replicas
  if (tid < ROWS) {
    float x0 = erff(out[row0 + tid]) * inv;
    for (int rep = 0; rep < R; ++rep)
      __hip_atomic_store(xbuf + (size_t)rep * N_RES + row0 + tid,
                         __float_as_uint(x0),
                         __ATOMIC_RELAXED, __HIP_MEMORY_SCOPE_AGENT);
    out[row0 + tid] = x0;
  }
  __syncthreads();

  for (int t = 1; t < T_SEQ; ++t) {
    const int p = t & 1;
    // own U[t] slot for row rml — issued before the poll, hides under it
    float u = out[(size_t)t * N_RES + row0 + rml];

    // poll own 8 x words of row t-1 in my replica (bit-30 sentinel test)
    const unsigned int* xr = xbuf + ((size_t)(t - 1) * R + rb) * N_RES + tid;
    unsigned int xb[8];
    unsigned int orv;
    do {
      #pragma unroll
      for (int j = 0; j < 8; ++j)
        xb[j] = __hip_atomic_load(xr + j * 256, __ATOMIC_RELAXED,
                                  __HIP_MEMORY_SCOPE_AGENT);
      orv  = (xb[0] | xb[1]) | (xb[2] | xb[3]);
      orv |= (xb[4] | xb[5]) | (xb[6] | xb[7]);
    } while (orv & 0x40000000u);

    // partial matvec: 16 rows x 8 cols
    float acc[ROWS];
    #pragma unroll
    for (int r = 0; r < ROWS; ++r) {
      acc[r] = w[r][0]*__uint_as_float(xb[0]) + w[r][1]*__uint_as_float(xb[1])
             + w[r][2]*__uint_as_float(xb[2]) + w[r][3]*__uint_as_float(xb[3])
             + w[r][4]*__uint_as_float(xb[4]) + w[r][5]*__uint_as_float(xb[5])
             + w[r][6]*__uint_as_float(xb[6]) + w[r][7]*__uint_as_float(xb[7]);
    }
    float s = fold_reduce16(acc, lane);   // lane holds full sum of row rml

    if (lane < ROWS) red[p][wave][rml] = s;
    __syncthreads();

    // lanes 0..15 of wave 0 finalize; row = rml (bijection on 0..15),
    // consistent with u. red gather at [w][rml] is bank-conflict-free.
    if (tid < ROWS) {
      float tot = red[p][0][rml] + red[p][1][rml]
                + red[p][2][rml] + red[p][3][rml];
      float xt = erff(u + tot) * inv;
      unsigned int xu = __float_as_uint(xt);
      unsigned int* dst = xbuf + (size_t)t * R * N_RES + row0 + rml;
      for (int rep = 0; rep < R; ++rep)
        __hip_atomic_store(dst + (size_t)rep * N_RES, xu,
                           __ATOMIC_RELAXED, __HIP_MEMORY_SCOPE_AGENT);
      out[(size_t)t * N_RES + row0 + rml] = xt;   // plain; after signals
    }
    // no second barrier: parity buffer + barrier-ordering bounds skew <= 1
  }
}

// ---------------- fallback (R2 flag barrier) if ws < 16 MiB ----------------
#define FSTR 4
__global__ __launch_bounds__(256, 1) void esn_recur_flags(
    const float* __restrict__ wres, float* out, int* ws)
{
  const int b = blockIdx.x;
  const int tid = threadIdx.x;
  const int lane = tid & 63;
  const int wave = tid >> 6;
  const int row0 = b * ROWS;
  const float inv = 0.022097086912079608f;

  float w[ROWS][8];
  #pragma unroll
  for (int r = 0; r < ROWS; ++r) {
    const float* p = wres + (size_t)(row0 + r) * N_RES + tid;
    #pragma unroll
    for (int j = 0; j < 8; ++j) w[r][j] = p[j * 256];
  }

  __shared__ float red[ROWS][4];
  int* flags = ws;

  if (tid < ROWS) {
    float u = out[row0 + tid];
    __hip_atomic_store(out + row0 + tid, erff(u) * inv,
                       __ATOMIC_RELAXED, __HIP_MEMORY_SCOPE_AGENT);
  }
  if (wave == 0) {
    asm volatile("s_waitcnt vmcnt(0)" ::: "memory");
    if (lane == 0)
      __hip_atomic_store(flags + b * FSTR, 1, __ATOMIC_RELAXED, __HIP_MEMORY_SCOPE_AGENT);
  }

  for (int t = 1; t < T_SEQ; ++t) {
    if (wave == 0) {
      const int* f0 = flags + lane * FSTR;
      const int* f1 = flags + (lane + 64) * FSTR;
      bool ok;
      do {
        int a = __hip_atomic_load(f0, __ATOMIC_RELAXED, __HIP_MEMORY_SCOPE_AGENT);
        int c = __hip_atomic_load(f1, __ATOMIC_RELAXED, __HIP_MEMORY_SCOPE_AGENT);
        ok = (a >= t) && (c >= t);
      } while (!__all(ok));
    }
    __syncthreads();

    float u = 0.f;
    if (tid < ROWS) u = out[(size_t)t * N_RES + row0 + tid];

    const float* xrow = out + (size_t)(t - 1) * N_RES + tid;
    float x[8];
    #pragma unroll
    for (int j = 0; j < 8; ++j)
      x[j] = __hip_atomic_load(xrow + j * 256, __ATOMIC_RELAXED, __HIP_MEMORY_SCOPE_AGENT);

    float acc[ROWS];
    #pragma unroll
    for (int r = 0; r < ROWS; ++r) {
      acc[r] = w[r][0]*x[0] + w[r][1]*x[1] + w[r][2]*x[2] + w[r][3]*x[3]
             + w[r][4]*x[4] + w[r][5]*x[5] + w[r][6]*x[6] + w[r][7]*x[7];
    }
    #pragma unroll
    for (int m = 1; m < 64; m <<= 1) {
      #pragma unroll
      for (int r = 0; r < ROWS; ++r)
        acc[r] += __shfl_xor(acc[r], m, 64);
    }
    if (lane == 0) {
      #pragma unroll
      for (int r = 0; r < ROWS; ++r) red[r][wave] = acc[r];
    }
    __syncthreads();
    if (tid < ROWS) {
      float s = red[tid][0] + red[tid][1] + red[tid][2] + red[tid][3];
      __hip_atomic_store(out + (size_t)t * N_RES + row0 + tid, erff(u + s) * inv,
                         __ATOMIC_RELAXED, __HIP_MEMORY_SCOPE_AGENT);
    }
    if (wave == 0) {
      asm volatile("s_waitcnt vmcnt(0)" ::: "memory");
      if (lane == 0)
        __hip_atomic_store(flags + b * FSTR, t + 1,
                           __ATOMIC_RELAXED, __HIP_MEMORY_SCOPE_AGENT);
    }
  }
}

extern "C" void kernel_launch(void* const* d_in, const int* in_sizes, int n_in,
                              void* d_out, int out_size, void* d_ws, size_t ws_size,
                              hipStream_t stream)
{
  const float* input = (const float*)d_in[0];
  const float* w_in  = (const float*)d_in[1];
  const float* w_res = (const float*)d_in[2];
  float* out = (float*)d_out;

  const size_t xbytes = (size_t)T_SEQ * N_RES * sizeof(float);  // 16 MiB

  dim3 g1(N_RES / 64, T_SEQ / 64), b1(256);
  hipLaunchKernelGGL(u_gemm, g1, b1, 0, stream, input, w_in, out);

  if (ws_size >= xbytes) {
    int R = 1;                                     // replicas (power of 2, <=4)
    while (R < 4 && (size_t)(2 * R) * xbytes <= ws_size) R *= 2;
    unsigned int* xbuf = (unsigned int*)d_ws;
    hipMemsetAsync(d_ws, 0x7F, (size_t)R * xbytes, stream);  // sentinel-fill
    void* args[] = { (void*)&w_res, (void*)&out, (void*)&xbuf, (void*)&R };
    hipLaunchCooperativeKernel((void*)esn_recur_v7, dim3(NB), dim3(256),
                               args, 0, stream);
  } else {
    int* ws = (int*)d_ws;
    size_t clr = ws_size < 4096 ? ws_size : 4096;
    hipMemsetAsync(d_ws, 0, clr, stream);
    void* args[] = { (void*)&w_res, (void*)&out, (void*)&ws };
    hipLaunchCooperativeKernel((void*)esn_recur_flags, dim3(NB), dim3(256),
                               args, 0, stream);
  }
}